// Round 1
// baseline (2335.558 us; speedup 1.0000x reference)
//
#include <hip/hip_runtime.h>

// Problem constants (from reference)
#define NN 15        // nodes == HID
#define HH 16384     // hidden channels == GRU seq len
#define G3 45        // 3*HID
#define EE 200       // edges
#define STRIDE 48    // padded GI row stride (floats); col 45 = W_lin[t]
#define CHUNK 8      // GI register double-buffer depth (steps)

// ---------------------------------------------------------------------------
// k_prep: GCN collapse + GI precompute.
//   a[n] = sum over edges(dst==n) dinv[src]*dinv[n]*x[src] + dinv[n]^2*x[n]
//   h1[n][t] = relu(a[n]*Wg[t] + bg[t])
//   giw[t][g] = b_ih[g] + sum_n h1[n][t]*W_ih[g][n]   (g in [0,45))
//   giw[t][45] = W_lin[t]
// ---------------------------------------------------------------------------
__global__ __launch_bounds__(256) void k_prep(
    const float* __restrict__ x, const int* __restrict__ ei,
    const float* __restrict__ Wg, const float* __restrict__ bg,
    const float* __restrict__ Wih, const float* __restrict__ bih,
    const float* __restrict__ Wlin, float* __restrict__ giw)
{
    __shared__ float s_dinv[NN], s_a[NN], s_wih[G3 * NN], s_bih[G3];
    const int tid = threadIdx.x;
    for (int i = tid; i < G3 * NN; i += 256) s_wih[i] = Wih[i];
    if (tid < G3) s_bih[tid] = bih[tid];
    if (tid < NN) {
        int deg = 1;  // self loop
        for (int e = 0; e < EE; ++e) deg += (ei[EE + e] == tid) ? 1 : 0;
        s_dinv[tid] = rsqrtf((float)deg);
    }
    __syncthreads();
    if (tid < NN) {
        const float di = s_dinv[tid];
        float acc = di * di * x[tid];  // self loop
        for (int e = 0; e < EE; ++e) {
            if (ei[EE + e] == tid) {
                const int s = ei[e];
                acc += s_dinv[s] * di * x[s];
            }
        }
        s_a[tid] = acc;
    }
    __syncthreads();
    const int t = blockIdx.x * 256 + tid;
    if (t >= HH) return;
    const float wg = Wg[t], bb = bg[t];
    float h1[NN];
    #pragma unroll
    for (int n = 0; n < NN; ++n) h1[n] = fmaxf(0.0f, fmaf(s_a[n], wg, bb));
    float* row = giw + t * STRIDE;
    #pragma unroll 9
    for (int g = 0; g < G3; ++g) {
        float a = s_bih[g];
        #pragma unroll
        for (int n = 0; n < NN; ++n) a = fmaf(h1[n], s_wih[g * NN + n], a);
        row[g] = a;
    }
    row[45] = Wlin[t];
}

// ---------------------------------------------------------------------------
// k_scan: the sequential GRU. One wave. h kept in SGPRs via v_readlane.
// Lane g in [0,15):  r-dot (row g) + n-dot (row 30+g); computes r, tanh, h_new
// Lane g in [15,30): z-dot (row g); z shuffled to lanes 0..14 (off crit path)
// Lane 45's GI stream-1 value is W_lin[t] (column 45) -> readlane broadcast.
// ---------------------------------------------------------------------------
__device__ __forceinline__ float sigm_f(float xx) {
    return __builtin_amdgcn_rcpf(1.0f + __builtin_amdgcn_exp2f(xx * -1.44269504f));
}
__device__ __forceinline__ float tanh_f(float xx) {
    // tanh(x) = 1 - 2/(1+e^{2x})
    return fmaf(-2.0f,
                __builtin_amdgcn_rcpf(1.0f + __builtin_amdgcn_exp2f(xx * 2.88539008f)),
                1.0f);
}

__device__ __forceinline__ void gru_step(
    float gi1, float gi2,
    const float (&w1)[NN], const float (&w2)[NN], float b1, float b2,
    float (&hs)[NN], float& vh, float& acc, int zsrc)
{
    // dual dot products, 3 accumulators each for ILP
    float a0 = fmaf(hs[0], w1[0], b1);
    float a1 = hs[1] * w1[1];
    float a2 = hs[2] * w1[2];
    float c0 = fmaf(hs[0], w2[0], b2);
    float c1 = hs[1] * w2[1];
    float c2 = hs[2] * w2[2];
    #pragma unroll
    for (int n = 3; n < NN; n += 3) {
        a0 = fmaf(hs[n],     w1[n],     a0);
        a1 = fmaf(hs[n + 1], w1[n + 1], a1);
        a2 = fmaf(hs[n + 2], w1[n + 2], a2);
        c0 = fmaf(hs[n],     w2[n],     c0);
        c1 = fmaf(hs[n + 1], w2[n + 1], c1);
        c2 = fmaf(hs[n + 2], w2[n + 2], c2);
    }
    const float gh1 = (a0 + a1) + a2;   // r (lanes 0..14) / z (lanes 15..29)
    const float gh2 = (c0 + c1) + c2;   // n-gate hh-dot (lanes 0..14)
    const float x1 = gh1 + gi1;
    const float sv = sigm_f(x1);        // r on lanes 0..14, z on lanes 15..29
    const float zz = __shfl(sv, zsrc);  // z for lanes 0..14; overlaps tanh chain
    const float x2 = fmaf(sv, gh2, gi2);       // i_n + r*(hh-dot incl b_hn)
    const float tv = tanh_f(x2);
    const float hnew = fmaf(zz, vh - tv, tv);  // (1-z)*n + z*h
    vh = hnew;
    const float wl = __builtin_bit_cast(float,
        __builtin_amdgcn_readlane(__builtin_bit_cast(int, gi1), 45));
    acc = fmaf(hnew, wl, acc);
    const int hb = __builtin_bit_cast(int, hnew);
    #pragma unroll
    for (int n = 0; n < NN; ++n)
        hs[n] = __builtin_bit_cast(float, __builtin_amdgcn_readlane(hb, n));
}

__global__ __launch_bounds__(64) void k_scan(
    const float* __restrict__ Whh, const float* __restrict__ bhh,
    const float* __restrict__ blin, const float* __restrict__ giw,
    float* __restrict__ out)
{
    const int lane = threadIdx.x;
    const int r1 = (lane < 30) ? lane : 29;          // clamped: junk lanes harmless
    const int r2 = (lane < 15) ? (30 + lane) : 44;
    float w1[NN], w2[NN];
    #pragma unroll
    for (int n = 0; n < NN; ++n) {
        w1[n] = Whh[r1 * NN + n];
        w2[n] = Whh[r2 * NN + n];
    }
    const float b1 = bhh[r1], b2 = bhh[r2];
    const int col1 = (lane <= 45) ? lane : 45;       // lane 45 -> W_lin column
    const int col2 = (lane < 15) ? (30 + lane) : 44;
    const int zsrc = (lane < 15) ? (lane + 15) : lane;

    float hs[NN];
    #pragma unroll
    for (int n = 0; n < NN; ++n) hs[n] = 0.0f;
    float vh = 0.0f, acc = 0.0f;

    float A1[CHUNK], A2[CHUNK], B1[CHUNK], B2[CHUNK];
    const float* p1 = giw + col1;
    const float* p2 = giw + col2;
    #pragma unroll
    for (int s = 0; s < CHUNK; ++s) { A1[s] = p1[s * STRIDE]; A2[s] = p2[s * STRIDE]; }

    for (int t0 = 0; t0 < HH; t0 += 2 * CHUNK) {
        // prefetch next chunk into B while computing A
        const float* q1 = p1 + (t0 + CHUNK) * STRIDE;
        const float* q2 = p2 + (t0 + CHUNK) * STRIDE;
        #pragma unroll
        for (int s = 0; s < CHUNK; ++s) { B1[s] = q1[s * STRIDE]; B2[s] = q2[s * STRIDE]; }
        #pragma unroll
        for (int s = 0; s < CHUNK; ++s)
            gru_step(A1[s], A2[s], w1, w2, b1, b2, hs, vh, acc, zsrc);
        const float* u1 = p1 + (t0 + 2 * CHUNK) * STRIDE;
        const float* u2 = p2 + (t0 + 2 * CHUNK) * STRIDE;
        #pragma unroll
        for (int s = 0; s < CHUNK; ++s) { A1[s] = u1[s * STRIDE]; A2[s] = u2[s * STRIDE]; }
        #pragma unroll
        for (int s = 0; s < CHUNK; ++s)
            gru_step(B1[s], B2[s], w1, w2, b1, b2, hs, vh, acc, zsrc);
    }
    if (lane < NN) out[lane] = acc + blin[0];
}

// ---------------------------------------------------------------------------
extern "C" void kernel_launch(void* const* d_in, const int* in_sizes, int n_in,
                              void* d_out, int out_size, void* d_ws, size_t ws_size,
                              hipStream_t stream)
{
    const float* x    = (const float*)d_in[0];
    const int*   ei   = (const int*)  d_in[1];
    const float* Wg   = (const float*)d_in[2];
    const float* bg   = (const float*)d_in[3];
    const float* Wih  = (const float*)d_in[4];
    const float* Whh  = (const float*)d_in[5];
    const float* bih  = (const float*)d_in[6];
    const float* bhh  = (const float*)d_in[7];
    const float* Wlin = (const float*)d_in[8];
    const float* blin = (const float*)d_in[9];
    float* out = (float*)d_out;
    float* giw = (float*)d_ws;   // needs (HH + 2*CHUNK)*STRIDE*4 ~= 3.15 MB

    k_prep<<<HH / 256, 256, 0, stream>>>(x, ei, Wg, bg, Wih, bih, Wlin, giw);
    k_scan<<<1, 64, 0, stream>>>(Whh, bhh, blin, giw, out);
}

// Round 3
// 2154.020 us; speedup vs baseline: 1.0843x; 1.0843x over previous
//
#include <hip/hip_runtime.h>

// Problem constants (from reference)
#define NN 15        // nodes == HID
#define HH 16384     // hidden channels == GRU seq len
#define G3 45        // 3*HID
#define EE 200       // edges
#define STRIDE 48    // padded GI row stride (floats); col 45 = W_lin[t]
#define CHUNK 8      // GI register double-buffer depth (steps)

typedef float f2 __attribute__((ext_vector_type(2)));

#define L2E 1.44269504f   // log2(e)

// ---------------------------------------------------------------------------
// k_prep: GCN collapse + GI precompute. ROUND-1 column layout (known good):
//   col g    = gi[g] * scale   (g in [0,45): r rows 0..14, z 15..29, n 30..44)
//              scale = -L2E for r/z, +2*L2E for n  (gate pre-scaling)
//   col 45   = W_lin[t]        (UNscaled)
// ---------------------------------------------------------------------------
__global__ __launch_bounds__(256) void k_prep(
    const float* __restrict__ x, const int* __restrict__ ei,
    const float* __restrict__ Wg, const float* __restrict__ bg,
    const float* __restrict__ Wih, const float* __restrict__ bih,
    const float* __restrict__ Wlin, float* __restrict__ giw)
{
    __shared__ float s_dinv[NN], s_a[NN], s_wih[G3 * NN], s_bih[G3];
    const int tid = threadIdx.x;
    for (int i = tid; i < G3 * NN; i += 256) s_wih[i] = Wih[i];
    if (tid < G3) s_bih[tid] = bih[tid];
    if (tid < NN) {
        int deg = 1;  // self loop
        for (int e = 0; e < EE; ++e) deg += (ei[EE + e] == tid) ? 1 : 0;
        s_dinv[tid] = rsqrtf((float)deg);
    }
    __syncthreads();
    if (tid < NN) {
        const float di = s_dinv[tid];
        float acc = di * di * x[tid];  // self loop
        for (int e = 0; e < EE; ++e) {
            if (ei[EE + e] == tid) {
                const int s = ei[e];
                acc += s_dinv[s] * di * x[s];
            }
        }
        s_a[tid] = acc;
    }
    __syncthreads();
    const int t = blockIdx.x * 256 + tid;
    if (t >= HH) return;
    const float wg = Wg[t], bb = bg[t];
    float h1[NN];
    #pragma unroll
    for (int n = 0; n < NN; ++n) h1[n] = fmaxf(0.0f, fmaf(s_a[n], wg, bb));
    float* row = giw + t * STRIDE;
    #pragma unroll 9
    for (int g = 0; g < G3; ++g) {
        float a = s_bih[g];
        #pragma unroll
        for (int n = 0; n < NN; ++n) a = fmaf(h1[n], s_wih[g * NN + n], a);
        const float scale = (g < 30) ? -L2E : (2.0f * L2E);
        row[g] = a * scale;
    }
    row[45] = Wlin[t];
}

// ---------------------------------------------------------------------------
// k_scan: sequential GRU, one wave, h broadcast via v_readlane. ROUND-1
// lane mapping (known good):
//   lane g in [0,15):   r-row g (stream1 col g) + n-row 30+g (stream2 col 30+g)
//   lane g in [15,30):  z-row g (stream1 col g); z shuffled to lanes 0..14
//   lane 45:            stream1 col 45 = W_lin[t] (readlane'd for the output)
// Weights/biases pre-scaled at load to match k_prep's gate pre-scaling.
// ---------------------------------------------------------------------------
__device__ __forceinline__ float bcast_f(float v, int lane) {
    return __builtin_bit_cast(float,
        __builtin_amdgcn_readlane(__builtin_bit_cast(int, v), lane));
}

__device__ __forceinline__ void gru_step(
    float gi1, float gi2,
    const f2 (&w1)[8], const f2 (&w2)[8], float b1, float b2,
    f2 (&hs)[8], float& vh, float& acc, int zsrc)
{
    // dual dot products as packed-f32 FMAs, 2 accumulators each
    f2 a0 = {b1, 0.0f}, a1 = {0.0f, 0.0f};
    f2 c0 = {b2, 0.0f}, c1 = {0.0f, 0.0f};
    #pragma unroll
    for (int k = 0; k < 8; k += 2) {
        a0 += hs[k]     * w1[k];
        a1 += hs[k + 1] * w1[k + 1];
        c0 += hs[k]     * w2[k];
        c1 += hs[k + 1] * w2[k + 1];
    }
    const float gh1 = (a0.x + a1.x) + (a0.y + a1.y);  // pre-scaled r/z hh-dot
    const float gh2 = (c0.x + c1.x) + (c0.y + c1.y);  // pre-scaled n hh-dot
    const float x1 = gh1 + gi1;                        // already * -L2E
    const float sv = __builtin_amdgcn_rcpf(1.0f + __builtin_amdgcn_exp2f(x1));
    const float zz = __shfl(sv, zsrc);                 // z; overlaps tanh chain
    const float x2 = fmaf(sv, gh2, gi2);               // already * 2*L2E
    const float tv = fmaf(-2.0f,
        __builtin_amdgcn_rcpf(1.0f + __builtin_amdgcn_exp2f(x2)), 1.0f);
    const float omz = 1.0f - zz;                       // off critical path
    const float pre = zz * vh;                         // off critical path
    const float hnew = fmaf(tv, omz, pre);             // 1 op after tanh
    vh = hnew;
    const float wl = bcast_f(gi1, 45);                 // W_lin[t] (unscaled)
    acc = fmaf(hnew, wl, acc);
    #pragma unroll
    for (int k = 0; k < 7; ++k) {
        hs[k].x = bcast_f(hnew, 2 * k);
        hs[k].y = bcast_f(hnew, 2 * k + 1);
    }
    hs[7].x = bcast_f(hnew, 14);
    hs[7].y = 0.0f;
}

__global__ __launch_bounds__(64, 1) void k_scan(
    const float* __restrict__ Whh, const float* __restrict__ bhh,
    const float* __restrict__ blin, const float* __restrict__ giw,
    float* __restrict__ out)
{
    const int lane = threadIdx.x;
    const int r1 = (lane < 30) ? lane : 29;          // clamped: junk lanes harmless
    const int r2 = (lane < 15) ? (30 + lane) : 44;
    f2 w1[8], w2[8];
    #pragma unroll
    for (int k = 0; k < 8; ++k) {
        const int i0 = 2 * k, i1 = 2 * k + 1;
        w1[k].x = Whh[r1 * NN + i0] * -L2E;
        w1[k].y = (i1 < NN) ? Whh[r1 * NN + i1] * -L2E : 0.0f;
        w2[k].x = Whh[r2 * NN + i0] * (2.0f * L2E);
        w2[k].y = (i1 < NN) ? Whh[r2 * NN + i1] * (2.0f * L2E) : 0.0f;
    }
    const float b1 = bhh[r1] * -L2E;
    const float b2 = bhh[r2] * (2.0f * L2E);
    const int col1 = (lane <= 45) ? lane : 45;       // lane 45 -> W_lin column
    const int col2 = (lane < 15) ? (30 + lane) : 44;
    const int zsrc = (lane < 15) ? (lane + 15) : lane;

    f2 hs[8];
    #pragma unroll
    for (int k = 0; k < 8; ++k) hs[k] = (f2){0.0f, 0.0f};
    float vh = 0.0f, acc = 0.0f;

    float A1[CHUNK], A2[CHUNK], B1[CHUNK], B2[CHUNK];
    const float* p1 = giw + col1;
    const float* p2 = giw + col2;
    #pragma unroll
    for (int s = 0; s < CHUNK; ++s) { A1[s] = p1[s * STRIDE]; A2[s] = p2[s * STRIDE]; }

    for (int t0 = 0; t0 < HH; t0 += 2 * CHUNK) {
        // prefetch next chunk into B while computing A
        #pragma unroll
        for (int s = 0; s < CHUNK; ++s) {
            B1[s] = p1[(t0 + CHUNK + s) * STRIDE];
            B2[s] = p2[(t0 + CHUNK + s) * STRIDE];
        }
        #pragma unroll
        for (int s = 0; s < CHUNK; ++s)
            gru_step(A1[s], A2[s], w1, w2, b1, b2, hs, vh, acc, zsrc);
        #pragma unroll
        for (int s = 0; s < CHUNK; ++s) {
            A1[s] = p1[(t0 + 2 * CHUNK + s) * STRIDE];
            A2[s] = p2[(t0 + 2 * CHUNK + s) * STRIDE];
        }
        #pragma unroll
        for (int s = 0; s < CHUNK; ++s)
            gru_step(B1[s], B2[s], w1, w2, b1, b2, hs, vh, acc, zsrc);
    }
    if (lane < NN) out[lane] = acc + blin[0];
}

// ---------------------------------------------------------------------------
extern "C" void kernel_launch(void* const* d_in, const int* in_sizes, int n_in,
                              void* d_out, int out_size, void* d_ws, size_t ws_size,
                              hipStream_t stream)
{
    const float* x    = (const float*)d_in[0];
    const int*   ei   = (const int*)  d_in[1];
    const float* Wg   = (const float*)d_in[2];
    const float* bg   = (const float*)d_in[3];
    const float* Wih  = (const float*)d_in[4];
    const float* Whh  = (const float*)d_in[5];
    const float* bih  = (const float*)d_in[6];
    const float* bhh  = (const float*)d_in[7];
    const float* Wlin = (const float*)d_in[8];
    const float* blin = (const float*)d_in[9];
    float* out = (float*)d_out;
    float* giw = (float*)d_ws;   // needs (HH + 2*CHUNK)*STRIDE*4 ~= 3.15 MB

    k_prep<<<HH / 256, 256, 0, stream>>>(x, ei, Wg, bg, Wih, bih, Wlin, giw);
    k_scan<<<1, 64, 0, stream>>>(Whh, bhh, blin, giw, out);
}